// Round 7
// baseline (879.370 us; speedup 1.0000x reference)
//
#include <hip/hip_runtime.h>
#include <hip/hip_bf16.h>

#define N_NODES 100000
#define N_EDGES 625000
#define D 128
#define N_LAYERS 10
#define SCAN_BLOCKS 98   // ceil(100000/1024)

typedef __attribute__((ext_vector_type(8))) short bf16x8;
typedef __attribute__((ext_vector_type(4))) float floatx4;

static __device__ __forceinline__ ushort f2bf(float f) {
    uint u = __float_as_uint(f);
    u += 0x7fff + ((u >> 16) & 1);   // round-to-nearest-even
    return (ushort)(u >> 16);
}
static __device__ __forceinline__ float bf2f(ushort h) {
    return __uint_as_float(((uint)h) << 16);
}
static __device__ __forceinline__ uint packbf(float lo, float hi) {
    return (uint)f2bf(lo) | ((uint)f2bf(hi) << 16);
}

// ---------------- CSR build (once per call) ----------------

__global__ void hist_kernel(const int* __restrict__ dst, int* __restrict__ deg) {
    int e = blockIdx.x * blockDim.x + threadIdx.x;
    if (e < N_EDGES) atomicAdd(&deg[dst[e]], 1);
}

__global__ void scanA_kernel(const int* __restrict__ deg, int* __restrict__ offsets,
                             int* __restrict__ blockSums) {
    __shared__ int s[1024];
    int tid = threadIdx.x;
    int i = blockIdx.x * 1024 + tid;
    int v = (i < N_NODES) ? deg[i] : 0;
    s[tid] = v;
    __syncthreads();
    for (int d = 1; d < 1024; d <<= 1) {
        int t = (tid >= d) ? s[tid - d] : 0;
        __syncthreads();
        s[tid] += t;
        __syncthreads();
    }
    if (i < N_NODES) offsets[i] = s[tid] - v;   // exclusive
    if (tid == 1023) blockSums[blockIdx.x] = s[1023];
}

__global__ void scanB_kernel(const int* __restrict__ blockSums, int* __restrict__ blockOffsets) {
    __shared__ int s[128];
    int tid = threadIdx.x;
    int v = (tid < SCAN_BLOCKS) ? blockSums[tid] : 0;
    s[tid] = v;
    __syncthreads();
    for (int d = 1; d < 128; d <<= 1) {
        int t = (tid >= d) ? s[tid - d] : 0;
        __syncthreads();
        s[tid] += t;
        __syncthreads();
    }
    blockOffsets[tid] = s[tid] - v;             // exclusive
}

__global__ void scanC_kernel(int* __restrict__ offsets, const int* __restrict__ blockOffsets) {
    int i = blockIdx.x * 1024 + threadIdx.x;
    if (i < N_NODES) offsets[i] += blockOffsets[blockIdx.x];
}

__global__ void invdeg_kernel(const int* __restrict__ deg, float* __restrict__ invdeg,
                              int* __restrict__ offsets) {
    int i = blockIdx.x * blockDim.x + threadIdx.x;
    if (i < N_NODES) {
        int d = deg[i];
        invdeg[i] = 1.0f / (float)(d > 0 ? d : 1);
    }
    if (i == 0) offsets[N_NODES] = N_EDGES;   // sentinel
}

__global__ void scatter_kernel(const int* __restrict__ src, const int* __restrict__ dst,
                               const int* __restrict__ offsets, int* __restrict__ fill,
                               int* __restrict__ srcSorted) {
    int e = blockIdx.x * blockDim.x + threadIdx.x;
    if (e < N_EDGES) {
        int d_ = dst[e];
        int pos = offsets[d_] + atomicAdd(&fill[d_], 1);
        srcSorted[pos] = src[e];
    }
}

// ---------------- W hi/lo split into B-fragment layout (once per call) ----------------
__global__ void wsplit_kernel(const float* __restrict__ Wl, const float* __restrict__ Wr,
                              ushort* __restrict__ Whi, ushort* __restrict__ Wlo) {
    int t = blockIdx.x * blockDim.x + threadIdx.x;
    if (t >= N_LAYERS * 4 * 16 * 64) return;
    int lane  = t & 63;
    int ntile = (t >> 6) & 15;
    int s     = (t >> 10) & 3;
    int layer = t >> 12;
    int n = ntile * 16 + (lane & 15);
    int kbase = s * 32 + (lane >> 4) * 8;
    const float* W = (n < 128) ? (Wl + (size_t)layer * D * D + n)
                               : (Wr + (size_t)layer * D * D + (n - 128));
    size_t off = (size_t)t * 8;
#pragma unroll
    for (int j = 0; j < 8; ++j) {
        float w = W[(size_t)(kbase + j) * D];
        ushort hh = f2bf(w);
        Whi[off + j] = hh;
        Wlo[off + j] = f2bf(w - bf2f(hh));
    }
}

// ntile ownership: base + {0,1,4,5}; waves 0,1 -> h, waves 2,3 -> z; lane holds col pairs
static __device__ __forceinline__ int ntmap(int wave, int nt) {
    int base = (wave < 2) ? wave * 2 : 8 + (wave - 2) * 2;
    return base + (nt & 1) + ((nt >> 1) << 2);
}

// ---------------- layer 0: h = x@Wl (packed bf16), z = x@Wr + b (packed bf16) ----------
// x is fp32 -> 3-pass hi/lo split A, M-tile 32.
__global__ __launch_bounds__(256) void gemm_hz(
        const float* __restrict__ X, const ushort* __restrict__ Whi,
        const ushort* __restrict__ Wlo, const float* __restrict__ bias,
        uint* __restrict__ h2out, uint* __restrict__ z2out) {
    __shared__ ushort Ahi[2][4 * 64 * 8];
    __shared__ ushort Alo[2][4 * 64 * 8];

    int tid  = threadIdx.x;
    int lane = tid & 63;
    int wave = tid >> 6;

    int r    = tid >> 4;
    int t0   = tid & 15;
    int s_st = t0 >> 2;
    int q_st = t0 & 3;
    int lanep = (q_st << 4) | r;
    int stIdx = (s_st * 64 + (lanep ^ (s_st << 2))) * 8;

    int q  = lane >> 4;
    int cc = lane & 15;

    int ntileMap[4];
#pragma unroll
    for (int nt = 0; nt < 4; ++nt) ntileMap[nt] = ntmap(wave, nt);

    float blo[2] = {0.f, 0.f}, bhi[2] = {0.f, 0.f};
    if (wave >= 2) {
#pragma unroll
        for (int p = 0; p < 2; ++p) {
            int c = (wave - 2) * 32 + p * 16 + cc;
            blo[p] = bias[c];
            bhi[p] = bias[c + 64];
        }
    }

    int row0 = blockIdx.x * 32;
#pragma unroll
    for (int st = 0; st < 2; ++st) {
        const float* xp = X + (size_t)(row0 + st * 16 + r) * D + t0 * 8;
        float4 v0 = *(const float4*)xp;
        float4 v1 = *(const float4*)(xp + 4);
        float a[8] = {v0.x, v0.y, v0.z, v0.w, v1.x, v1.y, v1.z, v1.w};
        ushort hi8[8], lo8[8];
#pragma unroll
        for (int j = 0; j < 8; ++j) {
            ushort hh = f2bf(a[j]);
            hi8[j] = hh;
            lo8[j] = f2bf(a[j] - bf2f(hh));
        }
        *(bf16x8*)&Ahi[st][stIdx] = *(bf16x8*)hi8;
        *(bf16x8*)&Alo[st][stIdx] = *(bf16x8*)lo8;
    }
    __syncthreads();

    floatx4 acc0[4], acc1[4];
#pragma unroll
    for (int nt = 0; nt < 4; ++nt) {
        acc0[nt] = (floatx4){0.f, 0.f, 0.f, 0.f};
        acc1[nt] = (floatx4){0.f, 0.f, 0.f, 0.f};
    }
#pragma unroll
    for (int s = 0; s < 4; ++s) {
        int aIdx = (s * 64 + (lane ^ (s << 2))) * 8;
        bf16x8 ah0 = *(const bf16x8*)&Ahi[0][aIdx];
        bf16x8 al0 = *(const bf16x8*)&Alo[0][aIdx];
        bf16x8 ah1 = *(const bf16x8*)&Ahi[1][aIdx];
        bf16x8 al1 = *(const bf16x8*)&Alo[1][aIdx];
#pragma unroll
        for (int nt = 0; nt < 4; ++nt) {
            size_t wo = ((size_t)(s * 16 + ntileMap[nt]) * 64 + lane) * 8;
            bf16x8 wh = *(const bf16x8*)&Whi[wo];
            bf16x8 wl = *(const bf16x8*)&Wlo[wo];
            acc0[nt] = __builtin_amdgcn_mfma_f32_16x16x32_bf16(ah0, wh, acc0[nt], 0, 0, 0);
            acc0[nt] = __builtin_amdgcn_mfma_f32_16x16x32_bf16(al0, wh, acc0[nt], 0, 0, 0);
            acc0[nt] = __builtin_amdgcn_mfma_f32_16x16x32_bf16(ah0, wl, acc0[nt], 0, 0, 0);
            acc1[nt] = __builtin_amdgcn_mfma_f32_16x16x32_bf16(ah1, wh, acc1[nt], 0, 0, 0);
            acc1[nt] = __builtin_amdgcn_mfma_f32_16x16x32_bf16(al1, wh, acc1[nt], 0, 0, 0);
            acc1[nt] = __builtin_amdgcn_mfma_f32_16x16x32_bf16(ah1, wl, acc1[nt], 0, 0, 0);
        }
    }

#pragma unroll
    for (int st = 0; st < 2; ++st) {
        floatx4* acc = st ? acc1 : acc0;
        int rowb = row0 + st * 16;
#pragma unroll
        for (int p = 0; p < 2; ++p) {
            if (wave < 2) {
                int c = wave * 32 + p * 16 + cc;
#pragma unroll
                for (int rr = 0; rr < 4; ++rr)
                    h2out[(size_t)(rowb + q * 4 + rr) * 64 + c] =
                        packbf(acc[p][rr], acc[p + 2][rr]);
            } else {
                int c = (wave - 2) * 32 + p * 16 + cc;
#pragma unroll
                for (int rr = 0; rr < 4; ++rr)
                    z2out[(size_t)(rowb + q * 4 + rr) * 64 + c] =
                        packbf(acc[p][rr] + blo[p], acc[p + 2][rr] + bhi[p]);
            }
        }
    }
}

// write one bf16 activation into A-fragment LDS
static __device__ __forceinline__ void frag_write1(ushort* __restrict__ A,
                                                   int m, int c, float v) {
    int s_ = c >> 5, q_ = (c >> 3) & 3, j_ = c & 7;
    A[(s_ * 64 + (((q_ << 4) | m) ^ (s_ << 2))) * 8 + j_] = f2bf(v);
}

// ---------------- fused layer L: act = relu(mean_agg(h) + z) [bf16];
//                  h' = act@Wl (packed), z' = act@Wr + b (packed, in-place) -------------
// M-tile 64: wave w aggregates rows of subtile w (16 nodes); MFMA: 4 subtiles x 4 ntiles.
__global__ __launch_bounds__(256) void fused_layer(
        const uint* __restrict__ h2in, const int* __restrict__ srcSorted,
        const int* __restrict__ offsets, const float* __restrict__ invdeg,
        uint* __restrict__ z2io, const ushort* __restrict__ Whi,
        const ushort* __restrict__ Wlo, const float* __restrict__ bias,
        uint* __restrict__ h2out) {
    __shared__ ushort Ahi[4][4 * 64 * 8];   // 4 KB per subtile = 16 KB

    int tid  = threadIdx.x;
    int lane = tid & 63;
    int wave = tid >> 6;
    int row0 = blockIdx.x * 64;

    // ---- phase 1: wave aggregates its 16 nodes (two 8-node groups) ----
    int n0 = row0 + wave * 16;
    int offv = offsets[min(n0 + min(lane, 16), N_NODES)];
    float invv = invdeg[min(n0 + min(lane, 15), N_NODES - 1)];
    ushort* Afrag = Ahi[wave];

#pragma unroll
    for (int g = 0; g < 2; ++g) {
        int base = g * 8;
        int offG0 = __shfl(offv, base, 64);
        int totalG = __shfl(offv, base + 8, 64) - offG0;
        int idxv = srcSorted[min(offG0 + ((lane < totalG) ? lane : 0), N_EDGES - 1)];
        // hoisted packed-z loads for the 8 nodes of this group
        uint zG[8];
#pragma unroll
        for (int i = 0; i < 8; ++i)
            zG[i] = z2io[(size_t)min(n0 + base + i, N_NODES - 1) * 64 + lane];

        for (int i = 0; i < 8; ++i) {
            int sRel = __shfl(offv, base + i, 64) - offG0;
            int eRel = __shfl(offv, base + i + 1, 64) - offG0;
            int cnt = eRel - sRel;
            float sx = 0.f, sy = 0.f;
            if (cnt > 0 && eRel <= 64) {
                for (int k = sRel; k < eRel; k += 8) {
                    int sidx[8];
#pragma unroll
                    for (int j = 0; j < 8; ++j) {
                        int kk = k + j;
                        sidx[j] = __shfl(idxv, (kk < eRel) ? kk : sRel, 64);
                    }
                    uint u[8];
#pragma unroll
                    for (int j = 0; j < 8; ++j)
                        u[j] = h2in[(size_t)sidx[j] * 64 + lane];
#pragma unroll
                    for (int j = 0; j < 8; ++j) {
                        float m = ((k + j) < eRel) ? 1.f : 0.f;
                        sx += m * __uint_as_float(u[j] << 16);
                        sy += m * __uint_as_float(u[j] & 0xffff0000u);
                    }
                }
            } else if (cnt > 0) {
                int offn = offG0 + sRel;
                int nv = cnt < 64 ? cnt : 64;
                int idxn = srcSorted[offn + ((lane < nv) ? lane : 0)];
                for (int k = 0; k < nv; k += 8) {
                    int sidx[8];
#pragma unroll
                    for (int j = 0; j < 8; ++j) {
                        int kk = k + j;
                        sidx[j] = __shfl(idxn, (kk < nv) ? kk : 0, 64);
                    }
                    uint u[8];
#pragma unroll
                    for (int j = 0; j < 8; ++j)
                        u[j] = h2in[(size_t)sidx[j] * 64 + lane];
#pragma unroll
                    for (int j = 0; j < 8; ++j) {
                        float m = ((k + j) < nv) ? 1.f : 0.f;
                        sx += m * __uint_as_float(u[j] << 16);
                        sy += m * __uint_as_float(u[j] & 0xffff0000u);
                    }
                }
                for (int k = 64; k < cnt; ++k) {
                    int s = srcSorted[offn + k];
                    uint u = h2in[(size_t)s * 64 + lane];
                    sx += __uint_as_float(u << 16);
                    sy += __uint_as_float(u & 0xffff0000u);
                }
            }
            float inv = __shfl(invv, base + i, 64);
            uint zp = zG[i];
            float ox = fmaxf(sx * inv + __uint_as_float(zp << 16), 0.f);
            float oy = fmaxf(sy * inv + __uint_as_float(zp & 0xffff0000u), 0.f);
            int m = base + i;
            frag_write1(Afrag, m, lane, ox);
            frag_write1(Afrag, m, lane + 64, oy);
        }
    }
    __syncthreads();

    // ---- phase 2: MFMA, 4 subtiles x 4 ntiles, 2-pass (Whi, Wlo) ----
    int q  = lane >> 4;
    int cc = lane & 15;
    int ntileMap[4];
#pragma unroll
    for (int nt = 0; nt < 4; ++nt) ntileMap[nt] = ntmap(wave, nt);

    float blo[2] = {0.f, 0.f}, bhi[2] = {0.f, 0.f};
    if (wave >= 2) {
#pragma unroll
        for (int p = 0; p < 2; ++p) {
            int c = (wave - 2) * 32 + p * 16 + cc;
            blo[p] = bias[c];
            bhi[p] = bias[c + 64];
        }
    }

    floatx4 acc[4][4];
#pragma unroll
    for (int st = 0; st < 4; ++st)
#pragma unroll
        for (int nt = 0; nt < 4; ++nt) acc[st][nt] = (floatx4){0.f, 0.f, 0.f, 0.f};

#pragma unroll
    for (int s = 0; s < 4; ++s) {
        int aIdx = (s * 64 + (lane ^ (s << 2))) * 8;
        bf16x8 a[4];
#pragma unroll
        for (int st = 0; st < 4; ++st) a[st] = *(const bf16x8*)&Ahi[st][aIdx];
#pragma unroll
        for (int nt = 0; nt < 4; ++nt) {
            size_t wo = ((size_t)(s * 16 + ntileMap[nt]) * 64 + lane) * 8;
            bf16x8 wh = *(const bf16x8*)&Whi[wo];
            bf16x8 wl = *(const bf16x8*)&Wlo[wo];
#pragma unroll
            for (int st = 0; st < 4; ++st) {
                acc[st][nt] = __builtin_amdgcn_mfma_f32_16x16x32_bf16(a[st], wh, acc[st][nt], 0, 0, 0);
                acc[st][nt] = __builtin_amdgcn_mfma_f32_16x16x32_bf16(a[st], wl, acc[st][nt], 0, 0, 0);
            }
        }
    }

#pragma unroll
    for (int st = 0; st < 4; ++st) {
        int rowb = row0 + st * 16;
#pragma unroll
        for (int p = 0; p < 2; ++p) {
            if (wave < 2) {
                int c = wave * 32 + p * 16 + cc;
#pragma unroll
                for (int rr = 0; rr < 4; ++rr) {
                    int row = rowb + q * 4 + rr;
                    if (row < N_NODES)
                        h2out[(size_t)row * 64 + c] = packbf(acc[st][p][rr], acc[st][p + 2][rr]);
                }
            } else {
                int c = (wave - 2) * 32 + p * 16 + cc;
#pragma unroll
                for (int rr = 0; rr < 4; ++rr) {
                    int row = rowb + q * 4 + rr;
                    if (row < N_NODES)
                        z2io[(size_t)row * 64 + c] =
                            packbf(acc[st][p][rr] + blo[p], acc[st][p + 2][rr] + bhi[p]);
                }
            }
        }
    }
}

// ---------------- final: out = mean_agg(h9) + z9 (no relu, fp32 out) -------------------
__global__ __launch_bounds__(256) void agg_add_kernel(
        const uint* __restrict__ h2, const int* __restrict__ srcSorted,
        const int* __restrict__ offsets, const int* __restrict__ deg,
        const float* __restrict__ invdeg, const uint* __restrict__ z2,
        float* __restrict__ out) {
    int node = blockIdx.x * 4 + (threadIdx.x >> 6);
    int lane = threadIdx.x & 63;
    int off = offsets[node];
    int cnt = deg[node];
    float sx = 0.f, sy = 0.f;
    if (cnt > 0) {
        int nv = cnt < 64 ? cnt : 64;
        int idxv = srcSorted[off + ((lane < nv) ? lane : 0)];
        for (int k = 0; k < nv; k += 8) {
            int sidx[8];
#pragma unroll
            for (int j = 0; j < 8; ++j) {
                int kk = k + j;
                sidx[j] = __shfl(idxv, (kk < nv) ? kk : 0, 64);
            }
            uint u[8];
#pragma unroll
            for (int j = 0; j < 8; ++j)
                u[j] = h2[(size_t)sidx[j] * 64 + lane];
#pragma unroll
            for (int j = 0; j < 8; ++j) {
                float m = ((k + j) < nv) ? 1.f : 0.f;
                sx += m * __uint_as_float(u[j] << 16);
                sy += m * __uint_as_float(u[j] & 0xffff0000u);
            }
        }
        for (int k = 64; k < cnt; ++k) {
            int s = srcSorted[off + k];
            uint u = h2[(size_t)s * 64 + lane];
            sx += __uint_as_float(u << 16);
            sy += __uint_as_float(u & 0xffff0000u);
        }
    }
    float inv = invdeg[node];
    uint zp = z2[(size_t)node * 64 + lane];
    out[(size_t)node * 128 + lane]      = sx * inv + __uint_as_float(zp << 16);
    out[(size_t)node * 128 + 64 + lane] = sy * inv + __uint_as_float(zp & 0xffff0000u);
}

extern "C" void kernel_launch(void* const* d_in, const int* in_sizes, int n_in,
                              void* d_out, int out_size, void* d_ws, size_t ws_size,
                              hipStream_t stream) {
    const float* x  = (const float*)d_in[0];
    const float* Wl = (const float*)d_in[1];
    const float* Wr = (const float*)d_in[2];
    const float* b  = (const float*)d_in[3];
    const int*   ei = (const int*)d_in[4];
    const int* src = ei;
    const int* dst = ei + N_EDGES;
    float* out = (float*)d_out;

    char* w = (char*)d_ws;
    auto alloc = [&](size_t bytes) -> char* {
        char* p = w;
        w += (bytes + 255) & ~(size_t)255;
        return p;
    };
    uint*   z2        = (uint*)alloc((size_t)N_NODES * 64 * 4);   // packed bf16 z col-pairs
    uint*   hbufA     = (uint*)alloc((size_t)N_NODES * 64 * 4);
    uint*   hbufB     = (uint*)alloc((size_t)N_NODES * 64 * 4);
    ushort* Whi       = (ushort*)alloc((size_t)N_LAYERS * 4 * 16 * 64 * 8 * 2);
    ushort* Wlo       = (ushort*)alloc((size_t)N_LAYERS * 4 * 16 * 64 * 8 * 2);
    int*    deg       = (int*)alloc((size_t)N_NODES * 4);
    int*    offsets   = (int*)alloc((size_t)(N_NODES + 1) * 4);
    int*    fill      = (int*)alloc((size_t)N_NODES * 4);
    int*    srcSorted = (int*)alloc((size_t)N_EDGES * 4);
    int*    blockSums = (int*)alloc(128 * 4);
    int*    blockOffs = (int*)alloc(128 * 4);
    float*  invdeg    = (float*)alloc((size_t)N_NODES * 4);

    hipMemsetAsync(deg, 0, (size_t)N_NODES * 4, stream);
    hipMemsetAsync(fill, 0, (size_t)N_NODES * 4, stream);

    hist_kernel<<<(N_EDGES + 255) / 256, 256, 0, stream>>>(dst, deg);
    scanA_kernel<<<SCAN_BLOCKS, 1024, 0, stream>>>(deg, offsets, blockSums);
    scanB_kernel<<<1, 128, 0, stream>>>(blockSums, blockOffs);
    scanC_kernel<<<SCAN_BLOCKS, 1024, 0, stream>>>(offsets, blockOffs);
    invdeg_kernel<<<(N_NODES + 255) / 256, 256, 0, stream>>>(deg, invdeg, offsets);
    scatter_kernel<<<(N_EDGES + 255) / 256, 256, 0, stream>>>(src, dst, offsets, fill, srcSorted);
    wsplit_kernel<<<(N_LAYERS * 4 * 16 * 64 + 255) / 256, 256, 0, stream>>>(Wl, Wr, Whi, Wlo);

    // layer 0 (x fp32 -> hi/lo A split)
    gemm_hz<<<N_NODES / 32, 256, 0, stream>>>(x, Whi, Wlo, b, hbufA, z2);
    // layers 1..9 fused
    uint* hin = hbufA;
    uint* hout = hbufB;
    for (int L = 1; L < N_LAYERS; ++L) {
        size_t woff = (size_t)L * 4 * 16 * 64 * 8;
        fused_layer<<<(N_NODES + 63) / 64, 256, 0, stream>>>(
            hin, srcSorted, offsets, invdeg, z2,
            Whi + woff, Wlo + woff, b + (size_t)L * D, hout);
        uint* t = hin; hin = hout; hout = t;
    }
    // final aggregation (h9 in `hin`)
    agg_add_kernel<<<N_NODES / 4, 256, 0, stream>>>(
        hin, srcSorted, offsets, deg, invdeg, z2, out);
}

// Round 8
// 751.753 us; speedup vs baseline: 1.1698x; 1.1698x over previous
//
#include <hip/hip_runtime.h>
#include <hip/hip_bf16.h>

#define N_NODES 100000
#define N_EDGES 625000
#define D 128
#define N_LAYERS 10
#define SCAN_BLOCKS 98   // ceil(100000/1024)

typedef __attribute__((ext_vector_type(8))) short bf16x8;
typedef __attribute__((ext_vector_type(4))) float floatx4;

static __device__ __forceinline__ ushort f2bf(float f) {
    uint u = __float_as_uint(f);
    u += 0x7fff + ((u >> 16) & 1);   // round-to-nearest-even
    return (ushort)(u >> 16);
}
static __device__ __forceinline__ float bf2f(ushort h) {
    return __uint_as_float(((uint)h) << 16);
}
static __device__ __forceinline__ uint packbf(float lo, float hi) {
    return (uint)f2bf(lo) | ((uint)f2bf(hi) << 16);
}

// ---------------- CSR build (once per call) ----------------

__global__ void hist_kernel(const int* __restrict__ dst, int* __restrict__ deg) {
    int e = blockIdx.x * blockDim.x + threadIdx.x;
    if (e < N_EDGES) atomicAdd(&deg[dst[e]], 1);
}

__global__ void scanA_kernel(const int* __restrict__ deg, int* __restrict__ offsets,
                             int* __restrict__ blockSums) {
    __shared__ int s[1024];
    int tid = threadIdx.x;
    int i = blockIdx.x * 1024 + tid;
    int v = (i < N_NODES) ? deg[i] : 0;
    s[tid] = v;
    __syncthreads();
    for (int d = 1; d < 1024; d <<= 1) {
        int t = (tid >= d) ? s[tid - d] : 0;
        __syncthreads();
        s[tid] += t;
        __syncthreads();
    }
    if (i < N_NODES) offsets[i] = s[tid] - v;   // exclusive
    if (tid == 1023) blockSums[blockIdx.x] = s[1023];
}

__global__ void scanB_kernel(const int* __restrict__ blockSums, int* __restrict__ blockOffsets) {
    __shared__ int s[128];
    int tid = threadIdx.x;
    int v = (tid < SCAN_BLOCKS) ? blockSums[tid] : 0;
    s[tid] = v;
    __syncthreads();
    for (int d = 1; d < 128; d <<= 1) {
        int t = (tid >= d) ? s[tid - d] : 0;
        __syncthreads();
        s[tid] += t;
        __syncthreads();
    }
    blockOffsets[tid] = s[tid] - v;             // exclusive
}

__global__ void scanC_kernel(int* __restrict__ offsets, const int* __restrict__ blockOffsets) {
    int i = blockIdx.x * 1024 + threadIdx.x;
    if (i < N_NODES) offsets[i] += blockOffsets[blockIdx.x];
}

__global__ void invdeg_kernel(const int* __restrict__ deg, float* __restrict__ invdeg,
                              int* __restrict__ offsets) {
    int i = blockIdx.x * blockDim.x + threadIdx.x;
    if (i < N_NODES) {
        int d = deg[i];
        invdeg[i] = 1.0f / (float)(d > 0 ? d : 1);
    }
    if (i == 0) offsets[N_NODES] = N_EDGES;   // sentinel
}

__global__ void scatter_kernel(const int* __restrict__ src, const int* __restrict__ dst,
                               const int* __restrict__ offsets, int* __restrict__ fill,
                               int* __restrict__ srcSorted) {
    int e = blockIdx.x * blockDim.x + threadIdx.x;
    if (e < N_EDGES) {
        int d_ = dst[e];
        int pos = offsets[d_] + atomicAdd(&fill[d_], 1);
        srcSorted[pos] = src[e];
    }
}

// ---------------- W hi/lo split into B-fragment layout (once per call) ----------------
__global__ void wsplit_kernel(const float* __restrict__ Wl, const float* __restrict__ Wr,
                              ushort* __restrict__ Whi, ushort* __restrict__ Wlo) {
    int t = blockIdx.x * blockDim.x + threadIdx.x;
    if (t >= N_LAYERS * 4 * 16 * 64) return;
    int lane  = t & 63;
    int ntile = (t >> 6) & 15;
    int s     = (t >> 10) & 3;
    int layer = t >> 12;
    int n = ntile * 16 + (lane & 15);
    int kbase = s * 32 + (lane >> 4) * 8;
    const float* W = (n < 128) ? (Wl + (size_t)layer * D * D + n)
                               : (Wr + (size_t)layer * D * D + (n - 128));
    size_t off = (size_t)t * 8;
#pragma unroll
    for (int j = 0; j < 8; ++j) {
        float w = W[(size_t)(kbase + j) * D];
        ushort hh = f2bf(w);
        Whi[off + j] = hh;
        Wlo[off + j] = f2bf(w - bf2f(hh));
    }
}

// ntile ownership: base + {0,1,4,5}; waves 0,1 -> h, waves 2,3 -> z; lane holds col pairs
static __device__ __forceinline__ int ntmap(int wave, int nt) {
    int base = (wave < 2) ? wave * 2 : 8 + (wave - 2) * 2;
    return base + (nt & 1) + ((nt >> 1) << 2);
}

// ---------------- layer 0: h = x@Wl (packed bf16), z = x@Wr + b (packed bf16) ----------
// x is fp32 -> 3-pass hi/lo split A, M-tile 32.
__global__ __launch_bounds__(256) void gemm_hz(
        const float* __restrict__ X, const ushort* __restrict__ Whi,
        const ushort* __restrict__ Wlo, const float* __restrict__ bias,
        uint* __restrict__ h2out, uint* __restrict__ z2out) {
    __shared__ ushort Ahi[2][4 * 64 * 8];
    __shared__ ushort Alo[2][4 * 64 * 8];

    int tid  = threadIdx.x;
    int lane = tid & 63;
    int wave = tid >> 6;

    int r    = tid >> 4;
    int t0   = tid & 15;
    int s_st = t0 >> 2;
    int q_st = t0 & 3;
    int lanep = (q_st << 4) | r;
    int stIdx = (s_st * 64 + (lanep ^ (s_st << 2))) * 8;

    int q  = lane >> 4;
    int cc = lane & 15;

    int ntileMap[4];
#pragma unroll
    for (int nt = 0; nt < 4; ++nt) ntileMap[nt] = ntmap(wave, nt);

    float blo[2] = {0.f, 0.f}, bhi[2] = {0.f, 0.f};
    if (wave >= 2) {
#pragma unroll
        for (int p = 0; p < 2; ++p) {
            int c = (wave - 2) * 32 + p * 16 + cc;
            blo[p] = bias[c];
            bhi[p] = bias[c + 64];
        }
    }

    int row0 = blockIdx.x * 32;
#pragma unroll
    for (int st = 0; st < 2; ++st) {
        const float* xp = X + (size_t)(row0 + st * 16 + r) * D + t0 * 8;
        float4 v0 = *(const float4*)xp;
        float4 v1 = *(const float4*)(xp + 4);
        float a[8] = {v0.x, v0.y, v0.z, v0.w, v1.x, v1.y, v1.z, v1.w};
        ushort hi8[8], lo8[8];
#pragma unroll
        for (int j = 0; j < 8; ++j) {
            ushort hh = f2bf(a[j]);
            hi8[j] = hh;
            lo8[j] = f2bf(a[j] - bf2f(hh));
        }
        *(bf16x8*)&Ahi[st][stIdx] = *(bf16x8*)hi8;
        *(bf16x8*)&Alo[st][stIdx] = *(bf16x8*)lo8;
    }
    __syncthreads();

    floatx4 acc0[4], acc1[4];
#pragma unroll
    for (int nt = 0; nt < 4; ++nt) {
        acc0[nt] = (floatx4){0.f, 0.f, 0.f, 0.f};
        acc1[nt] = (floatx4){0.f, 0.f, 0.f, 0.f};
    }
#pragma unroll
    for (int s = 0; s < 4; ++s) {
        int aIdx = (s * 64 + (lane ^ (s << 2))) * 8;
        bf16x8 ah0 = *(const bf16x8*)&Ahi[0][aIdx];
        bf16x8 al0 = *(const bf16x8*)&Alo[0][aIdx];
        bf16x8 ah1 = *(const bf16x8*)&Ahi[1][aIdx];
        bf16x8 al1 = *(const bf16x8*)&Alo[1][aIdx];
#pragma unroll
        for (int nt = 0; nt < 4; ++nt) {
            size_t wo = ((size_t)(s * 16 + ntileMap[nt]) * 64 + lane) * 8;
            bf16x8 wh = *(const bf16x8*)&Whi[wo];
            bf16x8 wl = *(const bf16x8*)&Wlo[wo];
            acc0[nt] = __builtin_amdgcn_mfma_f32_16x16x32_bf16(ah0, wh, acc0[nt], 0, 0, 0);
            acc0[nt] = __builtin_amdgcn_mfma_f32_16x16x32_bf16(al0, wh, acc0[nt], 0, 0, 0);
            acc0[nt] = __builtin_amdgcn_mfma_f32_16x16x32_bf16(ah0, wl, acc0[nt], 0, 0, 0);
            acc1[nt] = __builtin_amdgcn_mfma_f32_16x16x32_bf16(ah1, wh, acc1[nt], 0, 0, 0);
            acc1[nt] = __builtin_amdgcn_mfma_f32_16x16x32_bf16(al1, wh, acc1[nt], 0, 0, 0);
            acc1[nt] = __builtin_amdgcn_mfma_f32_16x16x32_bf16(ah1, wl, acc1[nt], 0, 0, 0);
        }
    }

#pragma unroll
    for (int st = 0; st < 2; ++st) {
        floatx4* acc = st ? acc1 : acc0;
        int rowb = row0 + st * 16;
#pragma unroll
        for (int p = 0; p < 2; ++p) {
            if (wave < 2) {
                int c = wave * 32 + p * 16 + cc;
#pragma unroll
                for (int rr = 0; rr < 4; ++rr)
                    h2out[(size_t)(rowb + q * 4 + rr) * 64 + c] =
                        packbf(acc[p][rr], acc[p + 2][rr]);
            } else {
                int c = (wave - 2) * 32 + p * 16 + cc;
#pragma unroll
                for (int rr = 0; rr < 4; ++rr)
                    z2out[(size_t)(rowb + q * 4 + rr) * 64 + c] =
                        packbf(acc[p][rr] + blo[p], acc[p + 2][rr] + bhi[p]);
            }
        }
    }
}

// write one bf16 activation into A-fragment LDS
static __device__ __forceinline__ void frag_write1(ushort* __restrict__ A,
                                                   int m, int c, float v) {
    int s_ = c >> 5, q_ = (c >> 3) & 3, j_ = c & 7;
    A[(s_ * 64 + (((q_ << 4) | m) ^ (s_ << 2))) * 8 + j_] = f2bf(v);
}

// ---------------- fused layer L: act = relu(mean_agg(h) + z) [bf16];
//                  h' = act@Wl (packed), z' = act@Wr + b (packed, in-place) -------------
// M-tile 32 (2 subtiles); wave w aggregates nodes w*8..w*8+7 into subtile w>>1.
__global__ __launch_bounds__(256) void fused_layer(
        const uint* __restrict__ h2in, const int* __restrict__ srcSorted,
        const int* __restrict__ offsets, const float* __restrict__ invdeg,
        uint* __restrict__ z2io, const ushort* __restrict__ Whi,
        const ushort* __restrict__ Wlo, const float* __restrict__ bias,
        uint* __restrict__ h2out) {
    __shared__ ushort Ahi[2][4 * 64 * 8];   // 4 KB per subtile = 8 KB

    int tid  = threadIdx.x;
    int lane = tid & 63;
    int wave = tid >> 6;
    int row0 = blockIdx.x * 32;

    // ---- phase 1: wave aggregates its 8 nodes ----
    int n0 = row0 + wave * 8;
    int offv = offsets[n0 + min(lane, 8)];          // lanes 0..8 hold offsets[n0..n0+8]
    float invv = invdeg[n0 + min(lane, 7)];         // lanes 0..7 hold invdeg
    int off0 = __shfl(offv, 0, 64);
    int total = __shfl(offv, 8, 64) - off0;
    int idxv = srcSorted[min(off0 + ((lane < total) ? lane : 0), N_EDGES - 1)];
    ushort* Afrag = Ahi[wave >> 1];

    for (int i = 0; i < 8; ++i) {
        int node = n0 + i;
        int sRel = __shfl(offv, i, 64) - off0;
        int eRel = __shfl(offv, i + 1, 64) - off0;
        int cnt = eRel - sRel;
        uint zp = z2io[(size_t)node * 64 + lane];   // issued before gather, overlaps
        float sx = 0.f, sy = 0.f;
        if (cnt > 0 && eRel <= 64) {
            for (int k = sRel; k < eRel; k += 8) {
                int sidx[8];
#pragma unroll
                for (int j = 0; j < 8; ++j) {
                    int kk = k + j;
                    sidx[j] = __shfl(idxv, (kk < eRel) ? kk : sRel, 64);
                }
                uint u[8];
#pragma unroll
                for (int j = 0; j < 8; ++j)
                    u[j] = h2in[(size_t)sidx[j] * 64 + lane];
#pragma unroll
                for (int j = 0; j < 8; ++j) {
                    float m = ((k + j) < eRel) ? 1.f : 0.f;
                    sx += m * __uint_as_float(u[j] << 16);
                    sy += m * __uint_as_float(u[j] & 0xffff0000u);
                }
            }
        } else if (cnt > 0) {
            int offn = off0 + sRel;
            int nv = cnt < 64 ? cnt : 64;
            int idxn = srcSorted[offn + ((lane < nv) ? lane : 0)];
            for (int k = 0; k < nv; k += 8) {
                int sidx[8];
#pragma unroll
                for (int j = 0; j < 8; ++j) {
                    int kk = k + j;
                    sidx[j] = __shfl(idxn, (kk < nv) ? kk : 0, 64);
                }
                uint u[8];
#pragma unroll
                for (int j = 0; j < 8; ++j)
                    u[j] = h2in[(size_t)sidx[j] * 64 + lane];
#pragma unroll
                for (int j = 0; j < 8; ++j) {
                    float m = ((k + j) < nv) ? 1.f : 0.f;
                    sx += m * __uint_as_float(u[j] << 16);
                    sy += m * __uint_as_float(u[j] & 0xffff0000u);
                }
            }
            for (int k = 64; k < cnt; ++k) {
                int s = srcSorted[offn + k];
                uint u = h2in[(size_t)s * 64 + lane];
                sx += __uint_as_float(u << 16);
                sy += __uint_as_float(u & 0xffff0000u);
            }
        }
        float inv = __shfl(invv, i, 64);
        float ox = fmaxf(sx * inv + __uint_as_float(zp << 16), 0.f);
        float oy = fmaxf(sy * inv + __uint_as_float(zp & 0xffff0000u), 0.f);
        int m = (wave & 1) * 8 + i;
        frag_write1(Afrag, m, lane, ox);
        frag_write1(Afrag, m, lane + 64, oy);
    }
    __syncthreads();

    // ---- phase 2: MFMA, 2 subtiles x 4 ntiles, 2-pass (Whi, Wlo) ----
    int q  = lane >> 4;
    int cc = lane & 15;
    int ntileMap[4];
#pragma unroll
    for (int nt = 0; nt < 4; ++nt) ntileMap[nt] = ntmap(wave, nt);

    float blo[2] = {0.f, 0.f}, bhi[2] = {0.f, 0.f};
    if (wave >= 2) {
#pragma unroll
        for (int p = 0; p < 2; ++p) {
            int c = (wave - 2) * 32 + p * 16 + cc;
            blo[p] = bias[c];
            bhi[p] = bias[c + 64];
        }
    }

    floatx4 acc[2][4];
#pragma unroll
    for (int st = 0; st < 2; ++st)
#pragma unroll
        for (int nt = 0; nt < 4; ++nt) acc[st][nt] = (floatx4){0.f, 0.f, 0.f, 0.f};

#pragma unroll
    for (int s = 0; s < 4; ++s) {
        int aIdx = (s * 64 + (lane ^ (s << 2))) * 8;
        bf16x8 a0 = *(const bf16x8*)&Ahi[0][aIdx];
        bf16x8 a1 = *(const bf16x8*)&Ahi[1][aIdx];
#pragma unroll
        for (int nt = 0; nt < 4; ++nt) {
            size_t wo = ((size_t)(s * 16 + ntileMap[nt]) * 64 + lane) * 8;
            bf16x8 wh = *(const bf16x8*)&Whi[wo];
            bf16x8 wl = *(const bf16x8*)&Wlo[wo];
            acc[0][nt] = __builtin_amdgcn_mfma_f32_16x16x32_bf16(a0, wh, acc[0][nt], 0, 0, 0);
            acc[0][nt] = __builtin_amdgcn_mfma_f32_16x16x32_bf16(a0, wl, acc[0][nt], 0, 0, 0);
            acc[1][nt] = __builtin_amdgcn_mfma_f32_16x16x32_bf16(a1, wh, acc[1][nt], 0, 0, 0);
            acc[1][nt] = __builtin_amdgcn_mfma_f32_16x16x32_bf16(a1, wl, acc[1][nt], 0, 0, 0);
        }
    }

#pragma unroll
    for (int st = 0; st < 2; ++st) {
        int rowb = row0 + st * 16;
#pragma unroll
        for (int p = 0; p < 2; ++p) {
            if (wave < 2) {
                int c = wave * 32 + p * 16 + cc;
#pragma unroll
                for (int rr = 0; rr < 4; ++rr)
                    h2out[(size_t)(rowb + q * 4 + rr) * 64 + c] =
                        packbf(acc[st][p][rr], acc[st][p + 2][rr]);
            } else {
                int c = (wave - 2) * 32 + p * 16 + cc;
#pragma unroll
                for (int rr = 0; rr < 4; ++rr)
                    z2io[(size_t)(rowb + q * 4 + rr) * 64 + c] =
                        packbf(acc[st][p][rr] + blo[p], acc[st][p + 2][rr] + bhi[p]);
            }
        }
    }
}

// ---------------- final: out = mean_agg(h9) + z9 (no relu, fp32 out) -------------------
__global__ __launch_bounds__(256) void agg_add_kernel(
        const uint* __restrict__ h2, const int* __restrict__ srcSorted,
        const int* __restrict__ offsets, const int* __restrict__ deg,
        const float* __restrict__ invdeg, const uint* __restrict__ z2,
        float* __restrict__ out) {
    int node = blockIdx.x * 4 + (threadIdx.x >> 6);
    int lane = threadIdx.x & 63;
    int off = offsets[node];
    int cnt = deg[node];
    float sx = 0.f, sy = 0.f;
    if (cnt > 0) {
        int nv = cnt < 64 ? cnt : 64;
        int idxv = srcSorted[off + ((lane < nv) ? lane : 0)];
        for (int k = 0; k < nv; k += 8) {
            int sidx[8];
#pragma unroll
            for (int j = 0; j < 8; ++j) {
                int kk = k + j;
                sidx[j] = __shfl(idxv, (kk < nv) ? kk : 0, 64);
            }
            uint u[8];
#pragma unroll
            for (int j = 0; j < 8; ++j)
                u[j] = h2[(size_t)sidx[j] * 64 + lane];
#pragma unroll
            for (int j = 0; j < 8; ++j) {
                float m = ((k + j) < nv) ? 1.f : 0.f;
                sx += m * __uint_as_float(u[j] << 16);
                sy += m * __uint_as_float(u[j] & 0xffff0000u);
            }
        }
        for (int k = 64; k < cnt; ++k) {
            int s = srcSorted[off + k];
            uint u = h2[(size_t)s * 64 + lane];
            sx += __uint_as_float(u << 16);
            sy += __uint_as_float(u & 0xffff0000u);
        }
    }
    float inv = invdeg[node];
    uint zp = z2[(size_t)node * 64 + lane];
    out[(size_t)node * 128 + lane]      = sx * inv + __uint_as_float(zp << 16);
    out[(size_t)node * 128 + 64 + lane] = sy * inv + __uint_as_float(zp & 0xffff0000u);
}

extern "C" void kernel_launch(void* const* d_in, const int* in_sizes, int n_in,
                              void* d_out, int out_size, void* d_ws, size_t ws_size,
                              hipStream_t stream) {
    const float* x  = (const float*)d_in[0];
    const float* Wl = (const float*)d_in[1];
    const float* Wr = (const float*)d_in[2];
    const float* b  = (const float*)d_in[3];
    const int*   ei = (const int*)d_in[4];
    const int* src = ei;
    const int* dst = ei + N_EDGES;
    float* out = (float*)d_out;

    char* w = (char*)d_ws;
    auto alloc = [&](size_t bytes) -> char* {
        char* p = w;
        w += (bytes + 255) & ~(size_t)255;
        return p;
    };
    uint*   z2        = (uint*)alloc((size_t)N_NODES * 64 * 4);   // packed bf16 z col-pairs
    uint*   hbufA     = (uint*)alloc((size_t)N_NODES * 64 * 4);
    uint*   hbufB     = (uint*)alloc((size_t)N_NODES * 64 * 4);
    ushort* Whi       = (ushort*)alloc((size_t)N_LAYERS * 4 * 16 * 64 * 8 * 2);
    ushort* Wlo       = (ushort*)alloc((size_t)N_LAYERS * 4 * 16 * 64 * 8 * 2);
    int*    deg       = (int*)alloc((size_t)N_NODES * 4);
    int*    offsets   = (int*)alloc((size_t)(N_NODES + 1) * 4);
    int*    fill      = (int*)alloc((size_t)N_NODES * 4);
    int*    srcSorted = (int*)alloc((size_t)N_EDGES * 4);
    int*    blockSums = (int*)alloc(128 * 4);
    int*    blockOffs = (int*)alloc(128 * 4);
    float*  invdeg    = (float*)alloc((size_t)N_NODES * 4);

    hipMemsetAsync(deg, 0, (size_t)N_NODES * 4, stream);
    hipMemsetAsync(fill, 0, (size_t)N_NODES * 4, stream);

    hist_kernel<<<(N_EDGES + 255) / 256, 256, 0, stream>>>(dst, deg);
    scanA_kernel<<<SCAN_BLOCKS, 1024, 0, stream>>>(deg, offsets, blockSums);
    scanB_kernel<<<1, 128, 0, stream>>>(blockSums, blockOffs);
    scanC_kernel<<<SCAN_BLOCKS, 1024, 0, stream>>>(offsets, blockOffs);
    invdeg_kernel<<<(N_NODES + 255) / 256, 256, 0, stream>>>(deg, invdeg, offsets);
    scatter_kernel<<<(N_EDGES + 255) / 256, 256, 0, stream>>>(src, dst, offsets, fill, srcSorted);
    wsplit_kernel<<<(N_LAYERS * 4 * 16 * 64 + 255) / 256, 256, 0, stream>>>(Wl, Wr, Whi, Wlo);

    // layer 0 (x fp32 -> hi/lo A split)
    gemm_hz<<<N_NODES / 32, 256, 0, stream>>>(x, Whi, Wlo, b, hbufA, z2);
    // layers 1..9 fused
    uint* hin = hbufA;
    uint* hout = hbufB;
    for (int L = 1; L < N_LAYERS; ++L) {
        size_t woff = (size_t)L * 4 * 16 * 64 * 8;
        fused_layer<<<N_NODES / 32, 256, 0, stream>>>(
            hin, srcSorted, offsets, invdeg, z2,
            Whi + woff, Wlo + woff, b + (size_t)L * D, hout);
        uint* t = hin; hin = hout; hout = t;
    }
    // final aggregation (h9 in `hin`)
    agg_add_kernel<<<N_NODES / 4, 256, 0, stream>>>(
        hin, srcSorted, offsets, deg, invdeg, z2, out);
}